// Round 1
// baseline (3313.735 us; speedup 1.0000x reference)
//
#include <hip/hip_runtime.h>
#include <math.h>

// ---------------------------------------------------------------------------
// DSS-Net style GNN forward. N=100000 nodes, D=32, E=3200000 edges, K=4.
// Restructured: edge MLP first layer split into node-level projections,
// second layer folded into GRU input matrix; CSR (by dst / by src) built once
// per launch so aggregation needs no float atomics.
// ---------------------------------------------------------------------------

// ---------------- one-time combine: fold W2s into GRU matrices --------------
__global__ void combine_kernel(const float* __restrict__ Wih, const float* __restrict__ bih,
    const float* __restrict__ toW2, const float* __restrict__ tob2,
    const float* __restrict__ frW2, const float* __restrict__ frb2,
    const float* __restrict__ lpW2, const float* __restrict__ lpb2,
    const float* __restrict__ lpW1,
    float* __restrict__ M_to, float* __restrict__ M_fr, float* __restrict__ M_lp,
    float* __restrict__ v_to, float* __restrict__ v_fr, float* __restrict__ bihp,
    float* __restrict__ Wlp1c) {
  int i = threadIdx.x;
  if (i < 96) {
    for (int k = 0; k < 32; k++) {
      float sto = 0.f, sfr = 0.f, slp = 0.f;
      for (int j = 0; j < 32; j++) {
        sto += Wih[i*131 + 32 + j] * toW2[j*32 + k];
        sfr += Wih[i*131 + 64 + j] * frW2[j*32 + k];
        slp += Wih[i*131 + 96 + j] * lpW2[j*32 + k];
      }
      M_to[i*32+k] = sto; M_fr[i*32+k] = sfr; M_lp[i*32+k] = slp;
    }
    float vt = 0.f, vf = 0.f, bl = 0.f;
    for (int j = 0; j < 32; j++) {
      vt += Wih[i*131 + 32 + j] * tob2[j];
      vf += Wih[i*131 + 64 + j] * frb2[j];
      bl += Wih[i*131 + 96 + j] * lpb2[j];
    }
    v_to[i] = vt; v_fr[i] = vf; bihp[i] = bih[i] + bl;
  }
  if (i < 32) {
    for (int k = 0; k < 32; k++)
      Wlp1c[i*32+k] = lpW1[i*65 + k] + lpW1[i*65 + 32 + k];  // H appears twice in lp input
  }
}

// ---------------- CSR build -------------------------------------------------
__global__ void count_kernel(const int* __restrict__ ei, const float* __restrict__ ea,
    int* __restrict__ cnt_dst, int* __restrict__ cnt_src, float* __restrict__ loop_col, int E) {
  int e = blockIdx.x*blockDim.x + threadIdx.x;
  if (e >= E) return;
  int s = ei[e], d = ei[E + e];
  if (s != d) {
    atomicAdd(&cnt_dst[d], 1);
    atomicAdd(&cnt_src[s], 1);
  } else {
    // loop_col = 1 - diag, diag = 1 + sum(self ea0)  ->  loop_col = -sum(self ea0)
    atomicAdd(&loop_col[s], -ea[2*e]);
  }
}

__global__ void scan_kernel(const int* __restrict__ cnt, int* __restrict__ row,
                            int* __restrict__ cur, int n) {
  __shared__ int buf[1024];
  __shared__ int carry_s;
  int tid = threadIdx.x;
  if (tid == 0) carry_s = 0;
  __syncthreads();
  for (int base = 0; base < n; base += 1024) {
    int i = base + tid;
    int v = (i < n) ? cnt[i] : 0;
    buf[tid] = v;
    __syncthreads();
    for (int off = 1; off < 1024; off <<= 1) {
      int t_ = (tid >= off) ? buf[tid - off] : 0;
      __syncthreads();
      buf[tid] += t_;
      __syncthreads();
    }
    int incl = buf[tid];
    int carry = carry_s;
    if (i < n) { int r = carry + incl - v; row[i] = r; cur[i] = r; }
    __syncthreads();
    if (tid == 1023) carry_s = carry + incl;
    __syncthreads();
  }
  if (tid == 0) row[n] = carry_s;
}

__global__ void fill_kernel(const int* __restrict__ ei, const float* __restrict__ ea,
    int* __restrict__ cur_to, int* __restrict__ cur_fr,
    int* __restrict__ oth_to, float2* __restrict__ ea_to,
    int* __restrict__ oth_fr, float2* __restrict__ ea_fr, int E) {
  int e = blockIdx.x*blockDim.x + threadIdx.x;
  if (e >= E) return;
  int s = ei[e], d = ei[E + e];
  if (s != d) {
    float2 a; a.x = ea[2*e]; a.y = ea[2*e+1];
    int pt = atomicAdd(&cur_to[d], 1);
    oth_to[pt] = s; ea_to[pt] = a;
    int pf = atomicAdd(&cur_fr[s], 1);
    oth_fr[pf] = d; ea_fr[pf] = a;
  }
}

// ---------------- per-iteration: node-level projections ---------------------
// thread = (node, f). LDS holds the five 32x32 matrices transposed (stride 33).
__global__ __launch_bounds__(256) void node_pre_kernel(
    const float* __restrict__ H, const float* __restrict__ loop_col,
    const float* __restrict__ toW1, const float* __restrict__ frW1,
    const float* __restrict__ Wlp1c, const float* __restrict__ lpW1, const float* __restrict__ lpb1,
    float* __restrict__ Pti, float* __restrict__ Ptj,
    float* __restrict__ Pfi, float* __restrict__ Pfj,
    float* __restrict__ hlp, int N) {
  __shared__ float w[5*1056];   // 5 matrices, [k][f] with stride 33
  __shared__ float hs[256];
  int t = threadIdx.x;
  #pragma unroll
  for (int r = 0; r < 4; r++) {
    int idx = r*256 + t;
    int fw = idx >> 5, k = idx & 31;
    w[0*1056 + k*33 + fw] = toW1[fw*66 + k];        // Wi_to (x_i = dst)
    w[1*1056 + k*33 + fw] = toW1[fw*66 + 32 + k];   // Wj_to (x_j = src)
    w[2*1056 + k*33 + fw] = frW1[fw*66 + k];        // Wi_fr (x_i = src)
    w[3*1056 + k*33 + fw] = frW1[fw*66 + 32 + k];   // Wj_fr (x_j = dst)
    w[4*1056 + k*33 + fw] = Wlp1c[fw*32 + k];
  }
  int node0 = blockIdx.x * 8;
  int gi = node0*32 + t;
  hs[t] = (gi < N*32) ? H[gi] : 0.f;
  __syncthreads();
  int nl = t >> 5, f = t & 31;
  int n = node0 + nl;
  if (n >= N) return;
  float a0=0.f, a1=0.f, a2=0.f, a3=0.f, a4=0.f;
  #pragma unroll
  for (int k = 0; k < 32; k++) {
    float hk = hs[nl*32 + k];
    a0 += w[0*1056 + k*33 + f]*hk;
    a1 += w[1*1056 + k*33 + f]*hk;
    a2 += w[2*1056 + k*33 + f]*hk;
    a3 += w[3*1056 + k*33 + f]*hk;
    a4 += w[4*1056 + k*33 + f]*hk;
  }
  int o = n*32 + f;
  Pti[o]=a0; Ptj[o]=a1; Pfi[o]=a2; Pfj[o]=a3;
  float hl = a4 + lpW1[f*65 + 64]*loop_col[n] + lpb1[f];
  hlp[o] = fmaxf(hl, 0.f);
}

// ---------------- per-iteration: edge aggregation (no atomics) --------------
// thread = (node, f); accumulates relu(Pi[n]+Pj[other]+We@ea+b1) over the
// node's CSR edge list, writes the masked mean of the hidden vector.
__global__ __launch_bounds__(256) void agg_kernel(
    const float* __restrict__ Pi, const float* __restrict__ Pj,
    const int* __restrict__ row, const int* __restrict__ oth,
    const float2* __restrict__ eal,
    const float* __restrict__ W1, const float* __restrict__ b1,
    float* __restrict__ acc_out, int N) {
  int t = blockIdx.x*blockDim.x + threadIdx.x;
  int n = t >> 5;
  if (n >= N) return;
  int f = t & 31;
  int start = row[n], end = row[n+1];
  float we0 = W1[f*66 + 64], we1 = W1[f*66 + 65];
  float base = Pi[n*32 + f] + b1[f];
  float s = 0.f;
  for (int i = start; i < end; i++) {
    int o = oth[i];
    float2 a = eal[i];
    float h = base + Pj[o*32 + f] + we0*a.x + we1*a.y;
    s += fmaxf(h, 0.f);
  }
  int c = end - start;
  acc_out[n*32 + f] = s / (float)(c > 0 ? c : 1);
}

// ---------------- per-iteration: GRU + H update + decode + loss -------------
__global__ __launch_bounds__(256) void node_update_kernel(
    float* __restrict__ H, const float* __restrict__ acc_to, const float* __restrict__ acc_fr,
    const float* __restrict__ hlp, const float* __restrict__ x, const float* __restrict__ y,
    const int* __restrict__ cnt_dst, const int* __restrict__ cnt_src,
    const float* __restrict__ Wih, const float* __restrict__ M_to, const float* __restrict__ M_fr,
    const float* __restrict__ M_lp, const float* __restrict__ v_to, const float* __restrict__ v_fr,
    const float* __restrict__ bihp, const float* __restrict__ bhh,
    const float* __restrict__ dW1, const float* __restrict__ db1,
    const float* __restrict__ dW2, const float* __restrict__ db2,
    float* __restrict__ Fout, float* __restrict__ loss_acc, int k_iter, int N) {
  int n = blockIdx.x*blockDim.x + threadIdx.x;
  float my_loss = 0.f;
  if (n < N) {
    float h[32], at[32], af[32], hl[32];
    const float4* p4;
    p4 = (const float4*)(H + n*32);
    #pragma unroll
    for (int q = 0; q < 8; q++) { float4 v = p4[q]; h[4*q]=v.x; h[4*q+1]=v.y; h[4*q+2]=v.z; h[4*q+3]=v.w; }
    p4 = (const float4*)(acc_to + n*32);
    #pragma unroll
    for (int q = 0; q < 8; q++) { float4 v = p4[q]; at[4*q]=v.x; at[4*q+1]=v.y; at[4*q+2]=v.z; at[4*q+3]=v.w; }
    p4 = (const float4*)(acc_fr + n*32);
    #pragma unroll
    for (int q = 0; q < 8; q++) { float4 v = p4[q]; af[4*q]=v.x; af[4*q+1]=v.y; af[4*q+2]=v.z; af[4*q+3]=v.w; }
    p4 = (const float4*)(hlp + n*32);
    #pragma unroll
    for (int q = 0; q < 8; q++) { float4 v = p4[q]; hl[4*q]=v.x; hl[4*q+1]=v.y; hl[4*q+2]=v.z; hl[4*q+3]=v.w; }
    float gt = cnt_dst[n] > 0 ? 1.f : 0.f;
    float gf = cnt_src[n] > 0 ? 1.f : 0.f;
    float x0 = x[n*3], x1 = x[n*3+1], x2 = x[n*3+2];

    #pragma unroll 1
    for (int f = 0; f < 32; f++) {
      const float* wr = Wih + f*131;
      const float* wz = Wih + (f+32)*131;
      const float* wn = Wih + (f+64)*131;
      float ar = bihp[f]    + gt*v_to[f]    + gf*v_fr[f];
      float az = bihp[f+32] + gt*v_to[f+32] + gf*v_fr[f+32];
      float an = bihp[f+64] + gt*v_to[f+64] + gf*v_fr[f+64];
      #pragma unroll
      for (int k = 0; k < 32; k++) { float v = h[k];  ar += wr[k]*v; az += wz[k]*v; an += wn[k]*v; }
      const float* mr = M_to + f*32; const float* mz = M_to + (f+32)*32; const float* mn = M_to + (f+64)*32;
      #pragma unroll
      for (int k = 0; k < 32; k++) { float v = at[k]; ar += mr[k]*v; az += mz[k]*v; an += mn[k]*v; }
      mr = M_fr + f*32; mz = M_fr + (f+32)*32; mn = M_fr + (f+64)*32;
      #pragma unroll
      for (int k = 0; k < 32; k++) { float v = af[k]; ar += mr[k]*v; az += mz[k]*v; an += mn[k]*v; }
      mr = M_lp + f*32; mz = M_lp + (f+32)*32; mn = M_lp + (f+64)*32;
      #pragma unroll
      for (int k = 0; k < 32; k++) { float v = hl[k]; ar += mr[k]*v; az += mz[k]*v; an += mn[k]*v; }
      ar += wr[128]*x0 + wr[129]*x1 + wr[130]*x2;
      az += wz[128]*x0 + wz[129]*x1 + wz[130]*x2;
      an += wn[128]*x0 + wn[129]*x1 + wn[130]*x2;
      float rr = 1.f/(1.f + __expf(-(ar + bhh[f])));
      float zz = 1.f/(1.f + __expf(-(az + bhh[f+32])));
      float nv = tanhf(an + rr*bhh[f+64]);
      float hold = H[n*32 + f];            // old h (dynamic f: read from global)
      H[n*32 + f] = (1.f - zz)*nv*0.5f + hold;
    }

    // decode on updated H
    float hn[32];
    p4 = (const float4*)(H + n*32);
    #pragma unroll
    for (int q = 0; q < 8; q++) { float4 v = p4[q]; hn[4*q]=v.x; hn[4*q+1]=v.y; hn[4*q+2]=v.z; hn[4*q+3]=v.w; }
    float F0 = db2[0], F1 = db2[1];
    #pragma unroll 1
    for (int f = 0; f < 32; f++) {
      float a = db1[f];
      const float* wd = dW1 + f*32;
      #pragma unroll
      for (int k = 0; k < 32; k++) a += wd[k]*hn[k];
      a = fmaxf(a, 0.f);
      F0 += dW2[f]*a;
      F1 += dW2[32+f]*a;
    }
    float2 fo; fo.x = F0; fo.y = F1;
    ((float2*)Fout)[n] = fo;
    float e0 = F0 - y[n*2], e1 = F1 - y[n*2+1];
    my_loss = e0*e0 + e1*e1;
  }
  // block reduce loss, one atomic per block
  #pragma unroll
  for (int off = 32; off > 0; off >>= 1) my_loss += __shfl_down(my_loss, off, 64);
  __shared__ float ls[4];
  int wid = threadIdx.x >> 6;
  if ((threadIdx.x & 63) == 0) ls[wid] = my_loss;
  __syncthreads();
  if (threadIdx.x == 0) atomicAdd(&loss_acc[k_iter], ls[0]+ls[1]+ls[2]+ls[3]);
}

__global__ void finalize_kernel(const float* __restrict__ loss_acc, float* __restrict__ out, int N) {
  if (threadIdx.x == 0 && blockIdx.x == 0) {
    float inv = 1.f/(2.f*(float)N);
    float l0 = loss_acc[0]*inv, l1 = loss_acc[1]*inv, l2 = loss_acc[2]*inv, l3 = loss_acc[3]*inv;
    out[0] = l0*0.729f + l1*0.81f + l2*0.9f + l3;   // gamma^{3,2,1,0}
    out[1] = l0; out[2] = l1; out[3] = l2; out[4] = l3;
  }
}

// ---------------------------------------------------------------------------
extern "C" void kernel_launch(void* const* d_in, const int* in_sizes, int n_in,
                              void* d_out, int out_size, void* d_ws, size_t ws_size,
                              hipStream_t stream) {
  const float* x    = (const float*)d_in[0];
  const float* y    = (const float*)d_in[1];
  const int*   ei   = (const int*)  d_in[2];
  const float* ea   = (const float*)d_in[3];
  const float* toW1 = (const float*)d_in[4];  const float* tob1 = (const float*)d_in[5];
  const float* toW2 = (const float*)d_in[6];  const float* tob2 = (const float*)d_in[7];
  const float* frW1 = (const float*)d_in[8];  const float* frb1 = (const float*)d_in[9];
  const float* frW2 = (const float*)d_in[10]; const float* frb2 = (const float*)d_in[11];
  const float* lpW1 = (const float*)d_in[12]; const float* lpb1 = (const float*)d_in[13];
  const float* lpW2 = (const float*)d_in[14]; const float* lpb2 = (const float*)d_in[15];
  const float* gWih = (const float*)d_in[16]; const float* gbih = (const float*)d_in[17];
  const float* gbhh = (const float*)d_in[19];           // gru_Whh (d_in[18]) is dead: h0 = 0
  const float* dW1  = (const float*)d_in[20]; const float* db1  = (const float*)d_in[21];
  const float* dW2  = (const float*)d_in[22]; const float* db2  = (const float*)d_in[23];
  const int N = in_sizes[0] / 3;
  const int E = in_sizes[3] / 2;

  char* p = (char*)d_ws;
  auto carve = [&](size_t bytes) -> void* {
    void* r = (void*)p;
    p += (bytes + 255) & ~(size_t)255;
    return r;
  };
  // zeroed region first (single memset)
  float* H        = (float*)carve((size_t)N*32*4);
  int*   cnt_dst  = (int*)  carve((size_t)N*4);
  int*   cnt_src  = (int*)  carve((size_t)N*4);
  float* loop_col = (float*)carve((size_t)N*4);
  float* loss_acc = (float*)carve(64);
  size_t zero_bytes = (size_t)(p - (char*)d_ws);
  int*    row_to = (int*)   carve((size_t)(N+1)*4);
  int*    row_fr = (int*)   carve((size_t)(N+1)*4);
  int*    cur_to = (int*)   carve((size_t)N*4);
  int*    cur_fr = (int*)   carve((size_t)N*4);
  int*    oth_to = (int*)   carve((size_t)E*4);
  int*    oth_fr = (int*)   carve((size_t)E*4);
  float2* ea_to  = (float2*)carve((size_t)E*8);
  float2* ea_fr  = (float2*)carve((size_t)E*8);
  float*  Pti    = (float*) carve((size_t)N*32*4);
  float*  Ptj    = (float*) carve((size_t)N*32*4);
  float*  Pfi    = (float*) carve((size_t)N*32*4);
  float*  Pfj    = (float*) carve((size_t)N*32*4);
  float*  hlp    = (float*) carve((size_t)N*32*4);
  float*  acc_to = (float*) carve((size_t)N*32*4);
  float*  acc_fr = (float*) carve((size_t)N*32*4);
  float*  M_to   = (float*) carve(96*32*4);
  float*  M_fr   = (float*) carve(96*32*4);
  float*  M_lp   = (float*) carve(96*32*4);
  float*  v_to   = (float*) carve(96*4);
  float*  v_fr   = (float*) carve(96*4);
  float*  bihp   = (float*) carve(96*4);
  float*  Wlp1c  = (float*) carve(32*32*4);
  // total ws use: ~182 MB

  hipMemsetAsync(d_ws, 0, zero_bytes, stream);
  combine_kernel<<<1, 128, 0, stream>>>(gWih, gbih, toW2, tob2, frW2, frb2, lpW2, lpb2, lpW1,
                                        M_to, M_fr, M_lp, v_to, v_fr, bihp, Wlp1c);
  count_kernel<<<(E+255)/256, 256, 0, stream>>>(ei, ea, cnt_dst, cnt_src, loop_col, E);
  scan_kernel<<<1, 1024, 0, stream>>>(cnt_dst, row_to, cur_to, N);
  scan_kernel<<<1, 1024, 0, stream>>>(cnt_src, row_fr, cur_fr, N);
  fill_kernel<<<(E+255)/256, 256, 0, stream>>>(ei, ea, cur_to, cur_fr,
                                               oth_to, ea_to, oth_fr, ea_fr, E);

  float* Fout     = (float*)d_out;
  float* loss_out = (float*)d_out + (size_t)N*2;

  for (int k = 0; k < 4; k++) {
    node_pre_kernel<<<(N+7)/8, 256, 0, stream>>>(H, loop_col, toW1, frW1, Wlp1c, lpW1, lpb1,
                                                 Pti, Ptj, Pfi, Pfj, hlp, N);
    // Phi_to: x_i = dst (agg @ dst), x_j = src
    agg_kernel<<<(N*32+255)/256, 256, 0, stream>>>(Pti, Ptj, row_to, oth_to, ea_to,
                                                   toW1, tob1, acc_to, N);
    // Phi_from: x_i = src (agg @ src), x_j = dst
    agg_kernel<<<(N*32+255)/256, 256, 0, stream>>>(Pfi, Pfj, row_fr, oth_fr, ea_fr,
                                                   frW1, frb1, acc_fr, N);
    node_update_kernel<<<(N+255)/256, 256, 0, stream>>>(H, acc_to, acc_fr, hlp, x, y,
        cnt_dst, cnt_src, gWih, M_to, M_fr, M_lp, v_to, v_fr, bihp, gbhh,
        dW1, db1, dW2, db2, Fout, loss_acc, k, N);
  }
  finalize_kernel<<<1, 64, 0, stream>>>(loss_acc, loss_out, N);
}

// Round 2
// 2723.038 us; speedup vs baseline: 1.2169x; 1.2169x over previous
//
#include <hip/hip_runtime.h>
#include <math.h>

// ---------------------------------------------------------------------------
// DSS-Net style GNN forward. N=100000 nodes, D=32, E=3200000 edges, K=4.
// R1: packed 16B CSR records (1 scattered write/edge/dir instead of 2),
// fast chunked single-block scan (both directions in one launch),
// unrolled agg gather loop.
// ---------------------------------------------------------------------------

// ---------------- one-time combine: fold W2s into GRU matrices --------------
__global__ void combine_kernel(const float* __restrict__ Wih, const float* __restrict__ bih,
    const float* __restrict__ toW2, const float* __restrict__ tob2,
    const float* __restrict__ frW2, const float* __restrict__ frb2,
    const float* __restrict__ lpW2, const float* __restrict__ lpb2,
    const float* __restrict__ lpW1,
    float* __restrict__ M_to, float* __restrict__ M_fr, float* __restrict__ M_lp,
    float* __restrict__ v_to, float* __restrict__ v_fr, float* __restrict__ bihp,
    float* __restrict__ Wlp1c) {
  int i = threadIdx.x;
  if (i < 96) {
    for (int k = 0; k < 32; k++) {
      float sto = 0.f, sfr = 0.f, slp = 0.f;
      for (int j = 0; j < 32; j++) {
        sto += Wih[i*131 + 32 + j] * toW2[j*32 + k];
        sfr += Wih[i*131 + 64 + j] * frW2[j*32 + k];
        slp += Wih[i*131 + 96 + j] * lpW2[j*32 + k];
      }
      M_to[i*32+k] = sto; M_fr[i*32+k] = sfr; M_lp[i*32+k] = slp;
    }
    float vt = 0.f, vf = 0.f, bl = 0.f;
    for (int j = 0; j < 32; j++) {
      vt += Wih[i*131 + 32 + j] * tob2[j];
      vf += Wih[i*131 + 64 + j] * frb2[j];
      bl += Wih[i*131 + 96 + j] * lpb2[j];
    }
    v_to[i] = vt; v_fr[i] = vf; bihp[i] = bih[i] + bl;
  }
  if (i < 32) {
    for (int k = 0; k < 32; k++)
      Wlp1c[i*32+k] = lpW1[i*65 + k] + lpW1[i*65 + 32 + k];  // H appears twice in lp input
  }
}

// ---------------- CSR build -------------------------------------------------
__global__ void count_kernel(const int* __restrict__ ei, const float* __restrict__ ea,
    int* __restrict__ cnt_dst, int* __restrict__ cnt_src, float* __restrict__ loop_col, int E) {
  int e = blockIdx.x*blockDim.x + threadIdx.x;
  if (e >= E) return;
  int s = ei[e], d = ei[E + e];
  if (s != d) {
    atomicAdd(&cnt_dst[d], 1);
    atomicAdd(&cnt_src[s], 1);
  } else {
    // loop_col = 1 - diag, diag = 1 + sum(self ea0)  ->  loop_col = -sum(self ea0)
    atomicAdd(&loop_col[s], -ea[2*e]);
  }
}

// chunked work-efficient scan: each thread owns a serial chunk, wave-scan the
// per-thread sums via shfl, 16-partial second level, then write running prefix.
__global__ __launch_bounds__(1024) void scan_pair_kernel(
    const int* __restrict__ cnt_a, int* __restrict__ row_a, int* __restrict__ cur_a,
    const int* __restrict__ cnt_b, int* __restrict__ row_b, int* __restrict__ cur_b, int n) {
  __shared__ int wsum[16];
  int tid = threadIdx.x;
  int chunk = (n + 1023) >> 10;
  int begin = tid * chunk;
  int end = begin + chunk; if (end > n) end = n;
  int lane = tid & 63, wid = tid >> 6;
  #pragma unroll 1
  for (int which = 0; which < 2; which++) {
    const int* cnt = which ? cnt_b : cnt_a;
    int* row = which ? row_b : row_a;
    int* cur = which ? cur_b : cur_a;
    int sum = 0;
    if (begin < n)
      for (int i = begin; i < end; i++) sum += cnt[i];
    int v = sum;
    #pragma unroll
    for (int off = 1; off < 64; off <<= 1) {
      int t2 = __shfl_up(v, off, 64);
      if (lane >= off) v += t2;
    }
    if (lane == 63) wsum[wid] = v;
    __syncthreads();
    if (tid < 64) {
      int w = (tid < 16) ? wsum[tid] : 0;
      #pragma unroll
      for (int off = 1; off < 16; off <<= 1) {
        int t2 = __shfl_up(w, off, 64);
        if (tid >= off) w += t2;
      }
      if (tid < 16) wsum[tid] = w;
    }
    __syncthreads();
    int excl = (v - sum) + (wid > 0 ? wsum[wid - 1] : 0);
    if (begin < n) {
      int run = excl;
      for (int i = begin; i < end; i++) { row[i] = run; cur[i] = run; run += cnt[i]; }
    }
    if (tid == 0) row[n] = wsum[15];
    __syncthreads();   // wsum reused next pass
  }
}

// packed record: .x = other node id (bits), .y = ea0, .z = ea1, .w unused
__global__ void fill_kernel(const int* __restrict__ ei, const float* __restrict__ ea,
    int* __restrict__ cur_to, int* __restrict__ cur_fr,
    float4* __restrict__ rec_to, float4* __restrict__ rec_fr, int E) {
  int e = blockIdx.x*blockDim.x + threadIdx.x;
  if (e >= E) return;
  int s = ei[e], d = ei[E + e];
  if (s != d) {
    float2 a = ((const float2*)ea)[e];
    int pt = atomicAdd(&cur_to[d], 1);
    rec_to[pt] = make_float4(__int_as_float(s), a.x, a.y, 0.f);
    int pf = atomicAdd(&cur_fr[s], 1);
    rec_fr[pf] = make_float4(__int_as_float(d), a.x, a.y, 0.f);
  }
}

// ---------------- per-iteration: node-level projections ---------------------
// thread = (node, f). LDS holds the five 32x32 matrices transposed (stride 33).
__global__ __launch_bounds__(256) void node_pre_kernel(
    const float* __restrict__ H, const float* __restrict__ loop_col,
    const float* __restrict__ toW1, const float* __restrict__ frW1,
    const float* __restrict__ Wlp1c, const float* __restrict__ lpW1, const float* __restrict__ lpb1,
    float* __restrict__ Pti, float* __restrict__ Ptj,
    float* __restrict__ Pfi, float* __restrict__ Pfj,
    float* __restrict__ hlp, int N) {
  __shared__ float w[5*1056];   // 5 matrices, [k][f] with stride 33
  __shared__ float hs[256];
  int t = threadIdx.x;
  #pragma unroll
  for (int r = 0; r < 4; r++) {
    int idx = r*256 + t;
    int fw = idx >> 5, k = idx & 31;
    w[0*1056 + k*33 + fw] = toW1[fw*66 + k];        // Wi_to (x_i = dst)
    w[1*1056 + k*33 + fw] = toW1[fw*66 + 32 + k];   // Wj_to (x_j = src)
    w[2*1056 + k*33 + fw] = frW1[fw*66 + k];        // Wi_fr (x_i = src)
    w[3*1056 + k*33 + fw] = frW1[fw*66 + 32 + k];   // Wj_fr (x_j = dst)
    w[4*1056 + k*33 + fw] = Wlp1c[fw*32 + k];
  }
  int node0 = blockIdx.x * 8;
  int gi = node0*32 + t;
  hs[t] = (gi < N*32) ? H[gi] : 0.f;
  __syncthreads();
  int nl = t >> 5, f = t & 31;
  int n = node0 + nl;
  if (n >= N) return;
  float a0=0.f, a1=0.f, a2=0.f, a3=0.f, a4=0.f;
  #pragma unroll
  for (int k = 0; k < 32; k++) {
    float hk = hs[nl*32 + k];
    a0 += w[0*1056 + k*33 + f]*hk;
    a1 += w[1*1056 + k*33 + f]*hk;
    a2 += w[2*1056 + k*33 + f]*hk;
    a3 += w[3*1056 + k*33 + f]*hk;
    a4 += w[4*1056 + k*33 + f]*hk;
  }
  int o = n*32 + f;
  Pti[o]=a0; Ptj[o]=a1; Pfi[o]=a2; Pfj[o]=a3;
  float hl = a4 + lpW1[f*65 + 64]*loop_col[n] + lpb1[f];
  hlp[o] = fmaxf(hl, 0.f);
}

// ---------------- per-iteration: edge aggregation (no atomics) --------------
// thread = (node, f); accumulates relu(Pi[n]+Pj[other]+We@ea+b1) over the
// node's CSR edge list, writes the masked mean of the hidden vector.
__global__ __launch_bounds__(256) void agg_kernel(
    const float* __restrict__ Pi, const float* __restrict__ Pj,
    const int* __restrict__ row, const float4* __restrict__ rec,
    const float* __restrict__ W1, const float* __restrict__ b1,
    float* __restrict__ acc_out, int N) {
  int t = blockIdx.x*blockDim.x + threadIdx.x;
  int n = t >> 5;
  if (n >= N) return;
  int f = t & 31;
  int start = row[n], end = row[n+1];
  float we0 = W1[f*66 + 64], we1 = W1[f*66 + 65];
  float base = Pi[n*32 + f] + b1[f];
  float s = 0.f;
  #pragma unroll 4
  for (int i = start; i < end; i++) {
    float4 r = rec[i];
    int o = __float_as_int(r.x);
    float h = base + Pj[o*32 + f] + we0*r.y + we1*r.z;
    s += fmaxf(h, 0.f);
  }
  int c = end - start;
  acc_out[n*32 + f] = s / (float)(c > 0 ? c : 1);
}

// ---------------- per-iteration: GRU + H update + decode + loss -------------
__global__ __launch_bounds__(256) void node_update_kernel(
    float* __restrict__ H, const float* __restrict__ acc_to, const float* __restrict__ acc_fr,
    const float* __restrict__ hlp, const float* __restrict__ x, const float* __restrict__ y,
    const int* __restrict__ cnt_dst, const int* __restrict__ cnt_src,
    const float* __restrict__ Wih, const float* __restrict__ M_to, const float* __restrict__ M_fr,
    const float* __restrict__ M_lp, const float* __restrict__ v_to, const float* __restrict__ v_fr,
    const float* __restrict__ bihp, const float* __restrict__ bhh,
    const float* __restrict__ dW1, const float* __restrict__ db1,
    const float* __restrict__ dW2, const float* __restrict__ db2,
    float* __restrict__ Fout, float* __restrict__ loss_acc, int k_iter, int N) {
  int n = blockIdx.x*blockDim.x + threadIdx.x;
  float my_loss = 0.f;
  if (n < N) {
    float h[32], at[32], af[32], hl[32];
    const float4* p4;
    p4 = (const float4*)(H + n*32);
    #pragma unroll
    for (int q = 0; q < 8; q++) { float4 v = p4[q]; h[4*q]=v.x; h[4*q+1]=v.y; h[4*q+2]=v.z; h[4*q+3]=v.w; }
    p4 = (const float4*)(acc_to + n*32);
    #pragma unroll
    for (int q = 0; q < 8; q++) { float4 v = p4[q]; at[4*q]=v.x; at[4*q+1]=v.y; at[4*q+2]=v.z; at[4*q+3]=v.w; }
    p4 = (const float4*)(acc_fr + n*32);
    #pragma unroll
    for (int q = 0; q < 8; q++) { float4 v = p4[q]; af[4*q]=v.x; af[4*q+1]=v.y; af[4*q+2]=v.z; af[4*q+3]=v.w; }
    p4 = (const float4*)(hlp + n*32);
    #pragma unroll
    for (int q = 0; q < 8; q++) { float4 v = p4[q]; hl[4*q]=v.x; hl[4*q+1]=v.y; hl[4*q+2]=v.z; hl[4*q+3]=v.w; }
    float gt = cnt_dst[n] > 0 ? 1.f : 0.f;
    float gf = cnt_src[n] > 0 ? 1.f : 0.f;
    float x0 = x[n*3], x1 = x[n*3+1], x2 = x[n*3+2];

    #pragma unroll 1
    for (int f = 0; f < 32; f++) {
      const float* wr = Wih + f*131;
      const float* wz = Wih + (f+32)*131;
      const float* wn = Wih + (f+64)*131;
      float ar = bihp[f]    + gt*v_to[f]    + gf*v_fr[f];
      float az = bihp[f+32] + gt*v_to[f+32] + gf*v_fr[f+32];
      float an = bihp[f+64] + gt*v_to[f+64] + gf*v_fr[f+64];
      #pragma unroll
      for (int k = 0; k < 32; k++) { float v = h[k];  ar += wr[k]*v; az += wz[k]*v; an += wn[k]*v; }
      const float* mr = M_to + f*32; const float* mz = M_to + (f+32)*32; const float* mn = M_to + (f+64)*32;
      #pragma unroll
      for (int k = 0; k < 32; k++) { float v = at[k]; ar += mr[k]*v; az += mz[k]*v; an += mn[k]*v; }
      mr = M_fr + f*32; mz = M_fr + (f+32)*32; mn = M_fr + (f+64)*32;
      #pragma unroll
      for (int k = 0; k < 32; k++) { float v = af[k]; ar += mr[k]*v; az += mz[k]*v; an += mn[k]*v; }
      mr = M_lp + f*32; mz = M_lp + (f+32)*32; mn = M_lp + (f+64)*32;
      #pragma unroll
      for (int k = 0; k < 32; k++) { float v = hl[k]; ar += mr[k]*v; az += mz[k]*v; an += mn[k]*v; }
      ar += wr[128]*x0 + wr[129]*x1 + wr[130]*x2;
      az += wz[128]*x0 + wz[129]*x1 + wz[130]*x2;
      an += wn[128]*x0 + wn[129]*x1 + wn[130]*x2;
      float rr = 1.f/(1.f + __expf(-(ar + bhh[f])));
      float zz = 1.f/(1.f + __expf(-(az + bhh[f+32])));
      float nv = tanhf(an + rr*bhh[f+64]);
      float hold = H[n*32 + f];            // old h (dynamic f: read from global)
      H[n*32 + f] = (1.f - zz)*nv*0.5f + hold;
    }

    // decode on updated H
    float hn[32];
    p4 = (const float4*)(H + n*32);
    #pragma unroll
    for (int q = 0; q < 8; q++) { float4 v = p4[q]; hn[4*q]=v.x; hn[4*q+1]=v.y; hn[4*q+2]=v.z; hn[4*q+3]=v.w; }
    float F0 = db2[0], F1 = db2[1];
    #pragma unroll 1
    for (int f = 0; f < 32; f++) {
      float a = db1[f];
      const float* wd = dW1 + f*32;
      #pragma unroll
      for (int k = 0; k < 32; k++) a += wd[k]*hn[k];
      a = fmaxf(a, 0.f);
      F0 += dW2[f]*a;
      F1 += dW2[32+f]*a;
    }
    float2 fo; fo.x = F0; fo.y = F1;
    ((float2*)Fout)[n] = fo;
    float e0 = F0 - y[n*2], e1 = F1 - y[n*2+1];
    my_loss = e0*e0 + e1*e1;
  }
  // block reduce loss, one atomic per block
  #pragma unroll
  for (int off = 32; off > 0; off >>= 1) my_loss += __shfl_down(my_loss, off, 64);
  __shared__ float ls[4];
  int wid = threadIdx.x >> 6;
  if ((threadIdx.x & 63) == 0) ls[wid] = my_loss;
  __syncthreads();
  if (threadIdx.x == 0) atomicAdd(&loss_acc[k_iter], ls[0]+ls[1]+ls[2]+ls[3]);
}

__global__ void finalize_kernel(const float* __restrict__ loss_acc, float* __restrict__ out, int N) {
  if (threadIdx.x == 0 && blockIdx.x == 0) {
    float inv = 1.f/(2.f*(float)N);
    float l0 = loss_acc[0]*inv, l1 = loss_acc[1]*inv, l2 = loss_acc[2]*inv, l3 = loss_acc[3]*inv;
    out[0] = l0*0.729f + l1*0.81f + l2*0.9f + l3;   // gamma^{3,2,1,0}
    out[1] = l0; out[2] = l1; out[3] = l2; out[4] = l3;
  }
}

// ---------------------------------------------------------------------------
extern "C" void kernel_launch(void* const* d_in, const int* in_sizes, int n_in,
                              void* d_out, int out_size, void* d_ws, size_t ws_size,
                              hipStream_t stream) {
  const float* x    = (const float*)d_in[0];
  const float* y    = (const float*)d_in[1];
  const int*   ei   = (const int*)  d_in[2];
  const float* ea   = (const float*)d_in[3];
  const float* toW1 = (const float*)d_in[4];  const float* tob1 = (const float*)d_in[5];
  const float* toW2 = (const float*)d_in[6];  const float* tob2 = (const float*)d_in[7];
  const float* frW1 = (const float*)d_in[8];  const float* frb1 = (const float*)d_in[9];
  const float* frW2 = (const float*)d_in[10]; const float* frb2 = (const float*)d_in[11];
  const float* lpW1 = (const float*)d_in[12]; const float* lpb1 = (const float*)d_in[13];
  const float* lpW2 = (const float*)d_in[14]; const float* lpb2 = (const float*)d_in[15];
  const float* gWih = (const float*)d_in[16]; const float* gbih = (const float*)d_in[17];
  const float* gbhh = (const float*)d_in[19];           // gru_Whh (d_in[18]) is dead: h0 = 0
  const float* dW1  = (const float*)d_in[20]; const float* db1  = (const float*)d_in[21];
  const float* dW2  = (const float*)d_in[22]; const float* db2  = (const float*)d_in[23];
  const int N = in_sizes[0] / 3;
  const int E = in_sizes[3] / 2;

  char* p = (char*)d_ws;
  auto carve = [&](size_t bytes) -> void* {
    void* r = (void*)p;
    p += (bytes + 255) & ~(size_t)255;
    return r;
  };
  // zeroed region first (single memset)
  float* H        = (float*)carve((size_t)N*32*4);
  int*   cnt_dst  = (int*)  carve((size_t)N*4);
  int*   cnt_src  = (int*)  carve((size_t)N*4);
  float* loop_col = (float*)carve((size_t)N*4);
  float* loss_acc = (float*)carve(64);
  size_t zero_bytes = (size_t)(p - (char*)d_ws);
  int*    row_to = (int*)   carve((size_t)(N+1)*4);
  int*    row_fr = (int*)   carve((size_t)(N+1)*4);
  int*    cur_to = (int*)   carve((size_t)N*4);
  int*    cur_fr = (int*)   carve((size_t)N*4);
  float4* rec_to = (float4*)carve((size_t)E*16);
  float4* rec_fr = (float4*)carve((size_t)E*16);
  float*  Pti    = (float*) carve((size_t)N*32*4);
  float*  Ptj    = (float*) carve((size_t)N*32*4);
  float*  Pfi    = (float*) carve((size_t)N*32*4);
  float*  Pfj    = (float*) carve((size_t)N*32*4);
  float*  hlp    = (float*) carve((size_t)N*32*4);
  float*  acc_to = (float*) carve((size_t)N*32*4);
  float*  acc_fr = (float*) carve((size_t)N*32*4);
  float*  M_to   = (float*) carve(96*32*4);
  float*  M_fr   = (float*) carve(96*32*4);
  float*  M_lp   = (float*) carve(96*32*4);
  float*  v_to   = (float*) carve(96*4);
  float*  v_fr   = (float*) carve(96*4);
  float*  bihp   = (float*) carve(96*4);
  float*  Wlp1c  = (float*) carve(32*32*4);
  // total ws use: ~208 MB

  hipMemsetAsync(d_ws, 0, zero_bytes, stream);
  combine_kernel<<<1, 128, 0, stream>>>(gWih, gbih, toW2, tob2, frW2, frb2, lpW2, lpb2, lpW1,
                                        M_to, M_fr, M_lp, v_to, v_fr, bihp, Wlp1c);
  count_kernel<<<(E+255)/256, 256, 0, stream>>>(ei, ea, cnt_dst, cnt_src, loop_col, E);
  scan_pair_kernel<<<1, 1024, 0, stream>>>(cnt_dst, row_to, cur_to,
                                           cnt_src, row_fr, cur_fr, N);
  fill_kernel<<<(E+255)/256, 256, 0, stream>>>(ei, ea, cur_to, cur_fr,
                                               rec_to, rec_fr, E);

  float* Fout     = (float*)d_out;
  float* loss_out = (float*)d_out + (size_t)N*2;

  for (int k = 0; k < 4; k++) {
    node_pre_kernel<<<(N+7)/8, 256, 0, stream>>>(H, loop_col, toW1, frW1, Wlp1c, lpW1, lpb1,
                                                 Pti, Ptj, Pfi, Pfj, hlp, N);
    // Phi_to: x_i = dst (agg @ dst), x_j = src
    agg_kernel<<<(N*32+255)/256, 256, 0, stream>>>(Pti, Ptj, row_to, rec_to,
                                                   toW1, tob1, acc_to, N);
    // Phi_from: x_i = src (agg @ src), x_j = dst
    agg_kernel<<<(N*32+255)/256, 256, 0, stream>>>(Pfi, Pfj, row_fr, rec_fr,
                                                   frW1, frb1, acc_fr, N);
    node_update_kernel<<<(N+255)/256, 256, 0, stream>>>(H, acc_to, acc_fr, hlp, x, y,
        cnt_dst, cnt_src, gWih, M_to, M_fr, M_lp, v_to, v_fr, bihp, gbhh,
        dW1, db1, dW2, db2, Fout, loss_acc, k, N);
  }
  finalize_kernel<<<1, 64, 0, stream>>>(loss_acc, loss_out, N);
}

// Round 3
// 1740.822 us; speedup vs baseline: 1.9035x; 1.5642x over previous
//
#include <hip/hip_runtime.h>
#include <math.h>

// ---------------------------------------------------------------------------
// DSS-Net style GNN forward. N=100000 nodes, D=32, E=3200000 edges, K=4.
// R3: binned CSR build (kills scattered-write line amplification + random
// count atomics), 8-byte edge records (id:17b|dlow:7b, ea as 2xbf16),
// parallel multi-block scan, parallelized weight-combine.
// ---------------------------------------------------------------------------

#define BSHIFT 7
#define BIN_W 128
#define CAP 4608   // per-bin record capacity; mean 4092, sigma ~64 -> +8 sigma

__device__ __forceinline__ unsigned int pack_bf(float x) {
  unsigned int u = __float_as_uint(x);
  u += 0x7fffu + ((u >> 16) & 1u);   // round-to-nearest-even
  return u >> 16;
}

// ---------------- one-time combine: fold W2s into GRU matrices --------------
// work items: [0,3072) M matrices, [3072,3168) v/bihp, [3168,4192) Wlp1c
__global__ void combine_kernel(const float* __restrict__ Wih, const float* __restrict__ bih,
    const float* __restrict__ toW2, const float* __restrict__ tob2,
    const float* __restrict__ frW2, const float* __restrict__ frb2,
    const float* __restrict__ lpW2, const float* __restrict__ lpb2,
    const float* __restrict__ lpW1,
    float* __restrict__ M_to, float* __restrict__ M_fr, float* __restrict__ M_lp,
    float* __restrict__ v_to, float* __restrict__ v_fr, float* __restrict__ bihp,
    float* __restrict__ Wlp1c) {
  int tid = blockIdx.x * blockDim.x + threadIdx.x;
  if (tid < 3072) {
    int i = tid >> 5, k = tid & 31;
    float sto = 0.f, sfr = 0.f, slp = 0.f;
    #pragma unroll
    for (int j = 0; j < 32; j++) {
      sto += Wih[i*131 + 32 + j] * toW2[j*32 + k];
      sfr += Wih[i*131 + 64 + j] * frW2[j*32 + k];
      slp += Wih[i*131 + 96 + j] * lpW2[j*32 + k];
    }
    M_to[i*32+k] = sto; M_fr[i*32+k] = sfr; M_lp[i*32+k] = slp;
  } else if (tid < 3168) {
    int i = tid - 3072;
    float vt = 0.f, vf = 0.f, bl = 0.f;
    #pragma unroll
    for (int j = 0; j < 32; j++) {
      vt += Wih[i*131 + 32 + j] * tob2[j];
      vf += Wih[i*131 + 64 + j] * frb2[j];
      bl += Wih[i*131 + 96 + j] * lpb2[j];
    }
    v_to[i] = vt; v_fr[i] = vf; bihp[i] = bih[i] + bl;
  } else if (tid < 4192) {
    int t2 = tid - 3168; int i = t2 >> 5, k = t2 & 31;
    Wlp1c[i*32+k] = lpW1[i*65 + k] + lpW1[i*65 + 32 + k];  // H appears twice
  }
}

// ---------------- K3: scatter edges into bins (LDS-staged reservation) ------
// binned record: .x = other_id | (owner_low7 << 17), .y = packed 2xbf16 ea
__global__ __launch_bounds__(256) void scatter_bin_kernel(
    const int* __restrict__ ei, const float* __restrict__ ea,
    int* __restrict__ cursor_to, int* __restrict__ cursor_fr,
    uint2* __restrict__ binned_to, uint2* __restrict__ binned_fr,
    float* __restrict__ loop_col, int E) {
  __shared__ int h_to[1024], h_fr[1024];
  __shared__ int b_to[1024], b_fr[1024];
  int t = threadIdx.x;
  for (int i = t; i < 1024; i += 256) { h_to[i] = 0; h_fr[i] = 0; }
  __syncthreads();
  int base_e = blockIdx.x * 2048;
  int s[8], d[8]; float2 a[8]; int rt[8], rf[8];
  #pragma unroll
  for (int j = 0; j < 8; j++) {
    int e = base_e + j*256 + t;
    s[j] = -1;
    if (e < E) {
      int ss = ei[e], dd = ei[E + e];
      if (ss != dd) {
        s[j] = ss; d[j] = dd;
        a[j] = ((const float2*)ea)[e];
        rt[j] = atomicAdd(&h_to[dd >> BSHIFT], 1);
        rf[j] = atomicAdd(&h_fr[ss >> BSHIFT], 1);
      } else {
        atomicAdd(&loop_col[ss], -ea[2*e]);   // loop_col = -sum(self ea0); rare
      }
    }
  }
  __syncthreads();
  for (int i = t; i < 1024; i += 256) {
    int c = h_to[i]; if (c) b_to[i] = atomicAdd(&cursor_to[i], c);
    c = h_fr[i];     if (c) b_fr[i] = atomicAdd(&cursor_fr[i], c);
  }
  __syncthreads();
  #pragma unroll
  for (int j = 0; j < 8; j++) {
    if (s[j] >= 0) {
      unsigned int ep = pack_bf(a[j].x) | (pack_bf(a[j].y) << 16);
      int bt = d[j] >> BSHIFT, bf = s[j] >> BSHIFT;
      int st = b_to[bt] + rt[j], sf = b_fr[bf] + rf[j];
      if (st < CAP) binned_to[(size_t)bt*CAP + st] =
          make_uint2((unsigned int)s[j] | ((unsigned int)(d[j] & 127) << 17), ep);
      if (sf < CAP) binned_fr[(size_t)bf*CAP + sf] =
          make_uint2((unsigned int)d[j] | ((unsigned int)(s[j] & 127) << 17), ep);
    }
  }
}

// ---------------- per-bin node counts (no global random atomics) ------------
__global__ __launch_bounds__(256) void bin_count_kernel(
    const uint2* __restrict__ binned, const int* __restrict__ cursor,
    int* __restrict__ cnt, int N) {
  __shared__ int c[BIN_W];
  int b = blockIdx.x;
  if (threadIdx.x < BIN_W) c[threadIdx.x] = 0;
  __syncthreads();
  int m = cursor[b]; if (m > CAP) m = CAP;
  const uint2* seg = binned + (size_t)b*CAP;
  for (int i = threadIdx.x; i < m; i += 256)
    atomicAdd(&c[seg[i].x >> 17], 1);
  __syncthreads();
  int n = (b << BSHIFT) + threadIdx.x;
  if (threadIdx.x < BIN_W && n < N) cnt[n] = c[threadIdx.x];
}

// ---------------- multi-block scan: partials -> mid -> apply ---------------
__global__ __launch_bounds__(256) void scan_part_kernel(
    const int* __restrict__ cnt_a, const int* __restrict__ cnt_b,
    int* __restrict__ part, int n, int G) {
  __shared__ int ws[4];
  int b = blockIdx.x, t = threadIdx.x, lane = t & 63, w = t >> 6;
  int base = b*1024 + t*4;
  for (int which = 0; which < 2; which++) {
    const int* cnt = which ? cnt_b : cnt_a;
    int sum = 0;
    #pragma unroll
    for (int j = 0; j < 4; j++) if (base + j < n) sum += cnt[base + j];
    #pragma unroll
    for (int off = 32; off; off >>= 1) sum += __shfl_down(sum, off, 64);
    if (lane == 0) ws[w] = sum;
    __syncthreads();
    if (t == 0) part[which*G + b] = ws[0] + ws[1] + ws[2] + ws[3];
    __syncthreads();
  }
}

__global__ __launch_bounds__(256) void scan_mid_kernel(
    int* __restrict__ part, int* __restrict__ row_a, int* __restrict__ row_b,
    int n, int G) {
  __shared__ int ws[2][4];
  int t = threadIdx.x, lane = t & 63, w = t >> 6;
  for (int which = 0; which < 2; which++) {
    int v = (t < G) ? part[which*G + t] : 0;
    int orig = v;
    #pragma unroll
    for (int off = 1; off < 64; off <<= 1) {
      int u = __shfl_up(v, off, 64);
      if (lane >= off) v += u;
    }
    if (lane == 63) ws[which][w] = v;
    __syncthreads();
    int wadd = 0;
    for (int i = 0; i < w; i++) wadd += ws[which][i];
    int incl = v + wadd;
    if (t < G) part[which*G + t] = incl - orig;   // exclusive
    if (t == G - 1) { int* row = which ? row_b : row_a; row[n] = incl; }
    __syncthreads();
  }
}

__global__ __launch_bounds__(256) void scan_apply_kernel(
    const int* __restrict__ cnt_a, const int* __restrict__ cnt_b,
    const int* __restrict__ part, int* __restrict__ row_a, int* __restrict__ row_b,
    int n, int G) {
  __shared__ int ws[4];
  int b = blockIdx.x, t = threadIdx.x, lane = t & 63, w = t >> 6;
  int base = b*1024 + t*4;
  for (int which = 0; which < 2; which++) {
    const int* cnt = which ? cnt_b : cnt_a;
    int* row = which ? row_b : row_a;
    int v0 = (base   < n) ? cnt[base]   : 0;
    int v1 = (base+1 < n) ? cnt[base+1] : 0;
    int v2 = (base+2 < n) ? cnt[base+2] : 0;
    int v3 = (base+3 < n) ? cnt[base+3] : 0;
    int tsum = v0 + v1 + v2 + v3;
    int v = tsum;
    #pragma unroll
    for (int off = 1; off < 64; off <<= 1) {
      int u = __shfl_up(v, off, 64);
      if (lane >= off) v += u;
    }
    if (lane == 63) ws[w] = v;
    __syncthreads();
    int wadd = 0;
    for (int i = 0; i < w; i++) wadd += ws[i];
    int excl = v - tsum + wadd + part[which*G + b];
    if (base   < n) row[base]   = excl;
    if (base+1 < n) row[base+1] = excl + v0;
    if (base+2 < n) row[base+2] = excl + v0 + v1;
    if (base+3 < n) row[base+3] = excl + v0 + v1 + v2;
    __syncthreads();
  }
}

// ---------------- place: bin-ordered -> node-CSR (one block per bin) --------
// final rec: .x = other_id, .y = packed ea
__global__ __launch_bounds__(256) void place_kernel(
    const uint2* __restrict__ binned, const int* __restrict__ cursor,
    const int* __restrict__ row, uint2* __restrict__ rec, int N) {
  __shared__ int cur[BIN_W];
  int b = blockIdx.x;
  int n0 = b << BSHIFT;
  if (threadIdx.x < BIN_W) {
    int n = n0 + threadIdx.x;
    cur[threadIdx.x] = (n < N) ? row[n] : 0;
  }
  __syncthreads();
  int m = cursor[b]; if (m > CAP) m = CAP;
  const uint2* seg = binned + (size_t)b*CAP;
  for (int i = threadIdx.x; i < m; i += 256) {
    uint2 r = seg[i];
    int pos = atomicAdd(&cur[r.x >> 17], 1);
    rec[pos] = make_uint2(r.x & 0x1ffffu, r.y);
  }
}

// ---------------- per-iteration: node-level projections ---------------------
__global__ __launch_bounds__(256) void node_pre_kernel(
    const float* __restrict__ H, const float* __restrict__ loop_col,
    const float* __restrict__ toW1, const float* __restrict__ frW1,
    const float* __restrict__ Wlp1c, const float* __restrict__ lpW1, const float* __restrict__ lpb1,
    float* __restrict__ Pti, float* __restrict__ Ptj,
    float* __restrict__ Pfi, float* __restrict__ Pfj,
    float* __restrict__ hlp, int N) {
  __shared__ float w[5*1056];   // 5 matrices, [k][f] stride 33
  __shared__ float hs[256];
  int t = threadIdx.x;
  #pragma unroll
  for (int r = 0; r < 4; r++) {
    int idx = r*256 + t;
    int fw = idx >> 5, k = idx & 31;
    w[0*1056 + k*33 + fw] = toW1[fw*66 + k];
    w[1*1056 + k*33 + fw] = toW1[fw*66 + 32 + k];
    w[2*1056 + k*33 + fw] = frW1[fw*66 + k];
    w[3*1056 + k*33 + fw] = frW1[fw*66 + 32 + k];
    w[4*1056 + k*33 + fw] = Wlp1c[fw*32 + k];
  }
  int node0 = blockIdx.x * 8;
  int gi = node0*32 + t;
  hs[t] = (gi < N*32) ? H[gi] : 0.f;
  __syncthreads();
  int nl = t >> 5, f = t & 31;
  int n = node0 + nl;
  if (n >= N) return;
  float a0=0.f, a1=0.f, a2=0.f, a3=0.f, a4=0.f;
  #pragma unroll
  for (int k = 0; k < 32; k++) {
    float hk = hs[nl*32 + k];
    a0 += w[0*1056 + k*33 + f]*hk;
    a1 += w[1*1056 + k*33 + f]*hk;
    a2 += w[2*1056 + k*33 + f]*hk;
    a3 += w[3*1056 + k*33 + f]*hk;
    a4 += w[4*1056 + k*33 + f]*hk;
  }
  int o = n*32 + f;
  Pti[o]=a0; Ptj[o]=a1; Pfi[o]=a2; Pfj[o]=a3;
  float hl = a4 + lpW1[f*65 + 64]*loop_col[n] + lpb1[f];
  hlp[o] = fmaxf(hl, 0.f);
}

// ---------------- per-iteration: edge aggregation (no atomics) --------------
__global__ __launch_bounds__(256) void agg_kernel(
    const float* __restrict__ Pi, const float* __restrict__ Pj,
    const int* __restrict__ row, const uint2* __restrict__ rec,
    const float* __restrict__ W1, const float* __restrict__ b1,
    float* __restrict__ acc_out, int N) {
  int t = blockIdx.x*blockDim.x + threadIdx.x;
  int n = t >> 5;
  if (n >= N) return;
  int f = t & 31;
  int start = row[n], end = row[n+1];
  float we0 = W1[f*66 + 64], we1 = W1[f*66 + 65];
  float base = Pi[n*32 + f] + b1[f];
  float s = 0.f;
  #pragma unroll 4
  for (int i = start; i < end; i++) {
    uint2 r = rec[i];
    int o = r.x;
    float e0 = __uint_as_float((r.y & 0xffffu) << 16);
    float e1 = __uint_as_float(r.y & 0xffff0000u);
    float h = base + Pj[o*32 + f] + we0*e0 + we1*e1;
    s += fmaxf(h, 0.f);
  }
  int c = end - start;
  acc_out[n*32 + f] = s / (float)(c > 0 ? c : 1);
}

// ---------------- per-iteration: GRU + H update + decode + loss -------------
__global__ __launch_bounds__(256) void node_update_kernel(
    float* __restrict__ H, const float* __restrict__ acc_to, const float* __restrict__ acc_fr,
    const float* __restrict__ hlp, const float* __restrict__ x, const float* __restrict__ y,
    const int* __restrict__ cnt_dst, const int* __restrict__ cnt_src,
    const float* __restrict__ Wih, const float* __restrict__ M_to, const float* __restrict__ M_fr,
    const float* __restrict__ M_lp, const float* __restrict__ v_to, const float* __restrict__ v_fr,
    const float* __restrict__ bihp, const float* __restrict__ bhh,
    const float* __restrict__ dW1, const float* __restrict__ db1,
    const float* __restrict__ dW2, const float* __restrict__ db2,
    float* __restrict__ Fout, float* __restrict__ loss_acc, int k_iter, int N) {
  int n = blockIdx.x*blockDim.x + threadIdx.x;
  float my_loss = 0.f;
  if (n < N) {
    float h[32], at[32], af[32], hl[32];
    const float4* p4;
    p4 = (const float4*)(H + n*32);
    #pragma unroll
    for (int q = 0; q < 8; q++) { float4 v = p4[q]; h[4*q]=v.x; h[4*q+1]=v.y; h[4*q+2]=v.z; h[4*q+3]=v.w; }
    p4 = (const float4*)(acc_to + n*32);
    #pragma unroll
    for (int q = 0; q < 8; q++) { float4 v = p4[q]; at[4*q]=v.x; at[4*q+1]=v.y; at[4*q+2]=v.z; at[4*q+3]=v.w; }
    p4 = (const float4*)(acc_fr + n*32);
    #pragma unroll
    for (int q = 0; q < 8; q++) { float4 v = p4[q]; af[4*q]=v.x; af[4*q+1]=v.y; af[4*q+2]=v.z; af[4*q+3]=v.w; }
    p4 = (const float4*)(hlp + n*32);
    #pragma unroll
    for (int q = 0; q < 8; q++) { float4 v = p4[q]; hl[4*q]=v.x; hl[4*q+1]=v.y; hl[4*q+2]=v.z; hl[4*q+3]=v.w; }
    float gt = cnt_dst[n] > 0 ? 1.f : 0.f;
    float gf = cnt_src[n] > 0 ? 1.f : 0.f;
    float x0 = x[n*3], x1 = x[n*3+1], x2 = x[n*3+2];

    #pragma unroll 1
    for (int f = 0; f < 32; f++) {
      const float* wr = Wih + f*131;
      const float* wz = Wih + (f+32)*131;
      const float* wn = Wih + (f+64)*131;
      float ar = bihp[f]    + gt*v_to[f]    + gf*v_fr[f];
      float az = bihp[f+32] + gt*v_to[f+32] + gf*v_fr[f+32];
      float an = bihp[f+64] + gt*v_to[f+64] + gf*v_fr[f+64];
      #pragma unroll
      for (int k = 0; k < 32; k++) { float v = h[k];  ar += wr[k]*v; az += wz[k]*v; an += wn[k]*v; }
      const float* mr = M_to + f*32; const float* mz = M_to + (f+32)*32; const float* mn = M_to + (f+64)*32;
      #pragma unroll
      for (int k = 0; k < 32; k++) { float v = at[k]; ar += mr[k]*v; az += mz[k]*v; an += mn[k]*v; }
      mr = M_fr + f*32; mz = M_fr + (f+32)*32; mn = M_fr + (f+64)*32;
      #pragma unroll
      for (int k = 0; k < 32; k++) { float v = af[k]; ar += mr[k]*v; az += mz[k]*v; an += mn[k]*v; }
      mr = M_lp + f*32; mz = M_lp + (f+32)*32; mn = M_lp + (f+64)*32;
      #pragma unroll
      for (int k = 0; k < 32; k++) { float v = hl[k]; ar += mr[k]*v; az += mz[k]*v; an += mn[k]*v; }
      ar += wr[128]*x0 + wr[129]*x1 + wr[130]*x2;
      az += wz[128]*x0 + wz[129]*x1 + wz[130]*x2;
      an += wn[128]*x0 + wn[129]*x1 + wn[130]*x2;
      float rr = 1.f/(1.f + __expf(-(ar + bhh[f])));
      float zz = 1.f/(1.f + __expf(-(az + bhh[f+32])));
      float nv = tanhf(an + rr*bhh[f+64]);
      float hold = H[n*32 + f];
      H[n*32 + f] = (1.f - zz)*nv*0.5f + hold;
    }

    float hn[32];
    p4 = (const float4*)(H + n*32);
    #pragma unroll
    for (int q = 0; q < 8; q++) { float4 v = p4[q]; hn[4*q]=v.x; hn[4*q+1]=v.y; hn[4*q+2]=v.z; hn[4*q+3]=v.w; }
    float F0 = db2[0], F1 = db2[1];
    #pragma unroll 1
    for (int f = 0; f < 32; f++) {
      float a = db1[f];
      const float* wd = dW1 + f*32;
      #pragma unroll
      for (int k = 0; k < 32; k++) a += wd[k]*hn[k];
      a = fmaxf(a, 0.f);
      F0 += dW2[f]*a;
      F1 += dW2[32+f]*a;
    }
    float2 fo; fo.x = F0; fo.y = F1;
    ((float2*)Fout)[n] = fo;
    float e0 = F0 - y[n*2], e1 = F1 - y[n*2+1];
    my_loss = e0*e0 + e1*e1;
  }
  #pragma unroll
  for (int off = 32; off > 0; off >>= 1) my_loss += __shfl_down(my_loss, off, 64);
  __shared__ float ls[4];
  int wid = threadIdx.x >> 6;
  if ((threadIdx.x & 63) == 0) ls[wid] = my_loss;
  __syncthreads();
  if (threadIdx.x == 0) atomicAdd(&loss_acc[k_iter], ls[0]+ls[1]+ls[2]+ls[3]);
}

__global__ void finalize_kernel(const float* __restrict__ loss_acc, float* __restrict__ out, int N) {
  if (threadIdx.x == 0 && blockIdx.x == 0) {
    float inv = 1.f/(2.f*(float)N);
    float l0 = loss_acc[0]*inv, l1 = loss_acc[1]*inv, l2 = loss_acc[2]*inv, l3 = loss_acc[3]*inv;
    out[0] = l0*0.729f + l1*0.81f + l2*0.9f + l3;   // gamma^{3,2,1,0}
    out[1] = l0; out[2] = l1; out[3] = l2; out[4] = l3;
  }
}

// ---------------------------------------------------------------------------
extern "C" void kernel_launch(void* const* d_in, const int* in_sizes, int n_in,
                              void* d_out, int out_size, void* d_ws, size_t ws_size,
                              hipStream_t stream) {
  const float* x    = (const float*)d_in[0];
  const float* y    = (const float*)d_in[1];
  const int*   ei   = (const int*)  d_in[2];
  const float* ea   = (const float*)d_in[3];
  const float* toW1 = (const float*)d_in[4];  const float* tob1 = (const float*)d_in[5];
  const float* toW2 = (const float*)d_in[6];  const float* tob2 = (const float*)d_in[7];
  const float* frW1 = (const float*)d_in[8];  const float* frb1 = (const float*)d_in[9];
  const float* frW2 = (const float*)d_in[10]; const float* frb2 = (const float*)d_in[11];
  const float* lpW1 = (const float*)d_in[12]; const float* lpb1 = (const float*)d_in[13];
  const float* lpW2 = (const float*)d_in[14]; const float* lpb2 = (const float*)d_in[15];
  const float* gWih = (const float*)d_in[16]; const float* gbih = (const float*)d_in[17];
  const float* gbhh = (const float*)d_in[19];           // gru_Whh dead: h0 = 0
  const float* dW1  = (const float*)d_in[20]; const float* db1  = (const float*)d_in[21];
  const float* dW2  = (const float*)d_in[22]; const float* db2  = (const float*)d_in[23];
  const int N = in_sizes[0] / 3;
  const int E = in_sizes[3] / 2;
  const int NB = (N + BIN_W - 1) >> BSHIFT;        // 782
  const int G  = (N + 1023) >> 10;                 // 98 scan blocks

  char* p = (char*)d_ws;
  auto carve = [&](size_t bytes) -> void* {
    void* r = (void*)p;
    p += (bytes + 255) & ~(size_t)255;
    return r;
  };
  // zeroed region first (single memset)
  float* H         = (float*)carve((size_t)N*32*4);
  float* loop_col  = (float*)carve((size_t)N*4);
  int*   cursor_to = (int*)  carve((size_t)NB*4);
  int*   cursor_fr = (int*)  carve((size_t)NB*4);
  float* loss_acc  = (float*)carve(64);
  size_t zero_bytes = (size_t)(p - (char*)d_ws);
  int*    row_to   = (int*)  carve((size_t)(N+1)*4);
  int*    row_fr   = (int*)  carve((size_t)(N+1)*4);
  int*    cnt_dst  = (int*)  carve((size_t)N*4);
  int*    cnt_src  = (int*)  carve((size_t)N*4);
  int*    part     = (int*)  carve((size_t)2*G*4);
  uint2*  binned_to= (uint2*)carve((size_t)NB*CAP*8);
  uint2*  binned_fr= (uint2*)carve((size_t)NB*CAP*8);
  uint2*  rec_to   = (uint2*)carve((size_t)E*8);
  uint2*  rec_fr   = (uint2*)carve((size_t)E*8);
  float*  Pti      = (float*)carve((size_t)N*32*4);
  float*  Ptj      = (float*)carve((size_t)N*32*4);
  float*  Pfi      = (float*)carve((size_t)N*32*4);
  float*  Pfj      = (float*)carve((size_t)N*32*4);
  float*  hlp      = (float*)carve((size_t)N*32*4);
  float*  acc_to   = (float*)carve((size_t)N*32*4);
  float*  acc_fr   = (float*)carve((size_t)N*32*4);
  float*  M_to     = (float*)carve(96*32*4);
  float*  M_fr     = (float*)carve(96*32*4);
  float*  M_lp     = (float*)carve(96*32*4);
  float*  v_to     = (float*)carve(96*4);
  float*  v_fr     = (float*)carve(96*4);
  float*  bihp     = (float*)carve(96*4);
  float*  Wlp1c    = (float*)carve(32*32*4);

  hipMemsetAsync(d_ws, 0, zero_bytes, stream);
  combine_kernel<<<17, 256, 0, stream>>>(gWih, gbih, toW2, tob2, frW2, frb2, lpW2, lpb2, lpW1,
                                         M_to, M_fr, M_lp, v_to, v_fr, bihp, Wlp1c);
  scatter_bin_kernel<<<(E+2047)/2048, 256, 0, stream>>>(ei, ea, cursor_to, cursor_fr,
                                                        binned_to, binned_fr, loop_col, E);
  bin_count_kernel<<<NB, 256, 0, stream>>>(binned_to, cursor_to, cnt_dst, N);
  bin_count_kernel<<<NB, 256, 0, stream>>>(binned_fr, cursor_fr, cnt_src, N);
  scan_part_kernel<<<G, 256, 0, stream>>>(cnt_dst, cnt_src, part, N, G);
  scan_mid_kernel<<<1, 256, 0, stream>>>(part, row_to, row_fr, N, G);
  scan_apply_kernel<<<G, 256, 0, stream>>>(cnt_dst, cnt_src, part, row_to, row_fr, N, G);
  place_kernel<<<NB, 256, 0, stream>>>(binned_to, cursor_to, row_to, rec_to, N);
  place_kernel<<<NB, 256, 0, stream>>>(binned_fr, cursor_fr, row_fr, rec_fr, N);

  float* Fout     = (float*)d_out;
  float* loss_out = (float*)d_out + (size_t)N*2;

  for (int k = 0; k < 4; k++) {
    node_pre_kernel<<<(N+7)/8, 256, 0, stream>>>(H, loop_col, toW1, frW1, Wlp1c, lpW1, lpb1,
                                                 Pti, Ptj, Pfi, Pfj, hlp, N);
    agg_kernel<<<(N*32+255)/256, 256, 0, stream>>>(Pti, Ptj, row_to, rec_to,
                                                   toW1, tob1, acc_to, N);
    agg_kernel<<<(N*32+255)/256, 256, 0, stream>>>(Pfi, Pfj, row_fr, rec_fr,
                                                   frW1, frb1, acc_fr, N);
    node_update_kernel<<<(N+255)/256, 256, 0, stream>>>(H, acc_to, acc_fr, hlp, x, y,
        cnt_dst, cnt_src, gWih, M_to, M_fr, M_lp, v_to, v_fr, bihp, gbhh,
        dW1, db1, dW2, db2, Fout, loss_acc, k, N);
  }
  finalize_kernel<<<1, 64, 0, stream>>>(loss_acc, loss_out, N);
}

// Round 4
// 1734.863 us; speedup vs baseline: 1.9101x; 1.0034x over previous
//
#include <hip/hip_runtime.h>
#include <math.h>

// ---------------------------------------------------------------------------
// DSS-Net style GNN forward. N=100000 nodes, D=32, E=3200000 edges, K=4.
// R4: node_update de-spilled (launch_bounds(128,1), LDS h-slice for the
// dynamically-indexed element); Pj projection arrays packed bf16 to halve
// the agg gather traffic.
// ---------------------------------------------------------------------------

#define BSHIFT 7
#define BIN_W 128
#define CAP 4608   // per-bin record capacity; mean 4092, sigma ~64 -> +8 sigma

__device__ __forceinline__ unsigned int pack_bf(float x) {
  unsigned int u = __float_as_uint(x);
  u += 0x7fffu + ((u >> 16) & 1u);   // round-to-nearest-even
  return u >> 16;
}

// ---------------- one-time combine: fold W2s into GRU matrices --------------
// work items: [0,3072) M matrices, [3072,3168) v/bihp, [3168,4192) Wlp1c
__global__ void combine_kernel(const float* __restrict__ Wih, const float* __restrict__ bih,
    const float* __restrict__ toW2, const float* __restrict__ tob2,
    const float* __restrict__ frW2, const float* __restrict__ frb2,
    const float* __restrict__ lpW2, const float* __restrict__ lpb2,
    const float* __restrict__ lpW1,
    float* __restrict__ M_to, float* __restrict__ M_fr, float* __restrict__ M_lp,
    float* __restrict__ v_to, float* __restrict__ v_fr, float* __restrict__ bihp,
    float* __restrict__ Wlp1c) {
  int tid = blockIdx.x * blockDim.x + threadIdx.x;
  if (tid < 3072) {
    int i = tid >> 5, k = tid & 31;
    float sto = 0.f, sfr = 0.f, slp = 0.f;
    #pragma unroll
    for (int j = 0; j < 32; j++) {
      sto += Wih[i*131 + 32 + j] * toW2[j*32 + k];
      sfr += Wih[i*131 + 64 + j] * frW2[j*32 + k];
      slp += Wih[i*131 + 96 + j] * lpW2[j*32 + k];
    }
    M_to[i*32+k] = sto; M_fr[i*32+k] = sfr; M_lp[i*32+k] = slp;
  } else if (tid < 3168) {
    int i = tid - 3072;
    float vt = 0.f, vf = 0.f, bl = 0.f;
    #pragma unroll
    for (int j = 0; j < 32; j++) {
      vt += Wih[i*131 + 32 + j] * tob2[j];
      vf += Wih[i*131 + 64 + j] * frb2[j];
      bl += Wih[i*131 + 96 + j] * lpb2[j];
    }
    v_to[i] = vt; v_fr[i] = vf; bihp[i] = bih[i] + bl;
  } else if (tid < 4192) {
    int t2 = tid - 3168; int i = t2 >> 5, k = t2 & 31;
    Wlp1c[i*32+k] = lpW1[i*65 + k] + lpW1[i*65 + 32 + k];  // H appears twice
  }
}

// ---------------- K3: scatter edges into bins (LDS-staged reservation) ------
// binned record: .x = other_id | (owner_low7 << 17), .y = packed 2xbf16 ea
__global__ __launch_bounds__(256) void scatter_bin_kernel(
    const int* __restrict__ ei, const float* __restrict__ ea,
    int* __restrict__ cursor_to, int* __restrict__ cursor_fr,
    uint2* __restrict__ binned_to, uint2* __restrict__ binned_fr,
    float* __restrict__ loop_col, int E) {
  __shared__ int h_to[1024], h_fr[1024];
  __shared__ int b_to[1024], b_fr[1024];
  int t = threadIdx.x;
  for (int i = t; i < 1024; i += 256) { h_to[i] = 0; h_fr[i] = 0; }
  __syncthreads();
  int base_e = blockIdx.x * 2048;
  int s[8], d[8]; float2 a[8]; int rt[8], rf[8];
  #pragma unroll
  for (int j = 0; j < 8; j++) {
    int e = base_e + j*256 + t;
    s[j] = -1;
    if (e < E) {
      int ss = ei[e], dd = ei[E + e];
      if (ss != dd) {
        s[j] = ss; d[j] = dd;
        a[j] = ((const float2*)ea)[e];
        rt[j] = atomicAdd(&h_to[dd >> BSHIFT], 1);
        rf[j] = atomicAdd(&h_fr[ss >> BSHIFT], 1);
      } else {
        atomicAdd(&loop_col[ss], -ea[2*e]);   // loop_col = -sum(self ea0); rare
      }
    }
  }
  __syncthreads();
  for (int i = t; i < 1024; i += 256) {
    int c = h_to[i]; if (c) b_to[i] = atomicAdd(&cursor_to[i], c);
    c = h_fr[i];     if (c) b_fr[i] = atomicAdd(&cursor_fr[i], c);
  }
  __syncthreads();
  #pragma unroll
  for (int j = 0; j < 8; j++) {
    if (s[j] >= 0) {
      unsigned int ep = pack_bf(a[j].x) | (pack_bf(a[j].y) << 16);
      int bt = d[j] >> BSHIFT, bf = s[j] >> BSHIFT;
      int st = b_to[bt] + rt[j], sf = b_fr[bf] + rf[j];
      if (st < CAP) binned_to[(size_t)bt*CAP + st] =
          make_uint2((unsigned int)s[j] | ((unsigned int)(d[j] & 127) << 17), ep);
      if (sf < CAP) binned_fr[(size_t)bf*CAP + sf] =
          make_uint2((unsigned int)d[j] | ((unsigned int)(s[j] & 127) << 17), ep);
    }
  }
}

// ---------------- per-bin node counts (no global random atomics) ------------
__global__ __launch_bounds__(256) void bin_count_kernel(
    const uint2* __restrict__ binned, const int* __restrict__ cursor,
    int* __restrict__ cnt, int N) {
  __shared__ int c[BIN_W];
  int b = blockIdx.x;
  if (threadIdx.x < BIN_W) c[threadIdx.x] = 0;
  __syncthreads();
  int m = cursor[b]; if (m > CAP) m = CAP;
  const uint2* seg = binned + (size_t)b*CAP;
  for (int i = threadIdx.x; i < m; i += 256)
    atomicAdd(&c[seg[i].x >> 17], 1);
  __syncthreads();
  int n = (b << BSHIFT) + threadIdx.x;
  if (threadIdx.x < BIN_W && n < N) cnt[n] = c[threadIdx.x];
}

// ---------------- multi-block scan: partials -> mid -> apply ---------------
__global__ __launch_bounds__(256) void scan_part_kernel(
    const int* __restrict__ cnt_a, const int* __restrict__ cnt_b,
    int* __restrict__ part, int n, int G) {
  __shared__ int ws[4];
  int b = blockIdx.x, t = threadIdx.x, lane = t & 63, w = t >> 6;
  int base = b*1024 + t*4;
  for (int which = 0; which < 2; which++) {
    const int* cnt = which ? cnt_b : cnt_a;
    int sum = 0;
    #pragma unroll
    for (int j = 0; j < 4; j++) if (base + j < n) sum += cnt[base + j];
    #pragma unroll
    for (int off = 32; off; off >>= 1) sum += __shfl_down(sum, off, 64);
    if (lane == 0) ws[w] = sum;
    __syncthreads();
    if (t == 0) part[which*G + b] = ws[0] + ws[1] + ws[2] + ws[3];
    __syncthreads();
  }
}

__global__ __launch_bounds__(256) void scan_mid_kernel(
    int* __restrict__ part, int* __restrict__ row_a, int* __restrict__ row_b,
    int n, int G) {
  __shared__ int ws[2][4];
  int t = threadIdx.x, lane = t & 63, w = t >> 6;
  for (int which = 0; which < 2; which++) {
    int v = (t < G) ? part[which*G + t] : 0;
    int orig = v;
    #pragma unroll
    for (int off = 1; off < 64; off <<= 1) {
      int u = __shfl_up(v, off, 64);
      if (lane >= off) v += u;
    }
    if (lane == 63) ws[which][w] = v;
    __syncthreads();
    int wadd = 0;
    for (int i = 0; i < w; i++) wadd += ws[which][i];
    int incl = v + wadd;
    if (t < G) part[which*G + t] = incl - orig;   // exclusive
    if (t == G - 1) { int* row = which ? row_b : row_a; row[n] = incl; }
    __syncthreads();
  }
}

__global__ __launch_bounds__(256) void scan_apply_kernel(
    const int* __restrict__ cnt_a, const int* __restrict__ cnt_b,
    const int* __restrict__ part, int* __restrict__ row_a, int* __restrict__ row_b,
    int n, int G) {
  __shared__ int ws[4];
  int b = blockIdx.x, t = threadIdx.x, lane = t & 63, w = t >> 6;
  int base = b*1024 + t*4;
  for (int which = 0; which < 2; which++) {
    const int* cnt = which ? cnt_b : cnt_a;
    int* row = which ? row_b : row_a;
    int v0 = (base   < n) ? cnt[base]   : 0;
    int v1 = (base+1 < n) ? cnt[base+1] : 0;
    int v2 = (base+2 < n) ? cnt[base+2] : 0;
    int v3 = (base+3 < n) ? cnt[base+3] : 0;
    int tsum = v0 + v1 + v2 + v3;
    int v = tsum;
    #pragma unroll
    for (int off = 1; off < 64; off <<= 1) {
      int u = __shfl_up(v, off, 64);
      if (lane >= off) v += u;
    }
    if (lane == 63) ws[w] = v;
    __syncthreads();
    int wadd = 0;
    for (int i = 0; i < w; i++) wadd += ws[i];
    int excl = v - tsum + wadd + part[which*G + b];
    if (base   < n) row[base]   = excl;
    if (base+1 < n) row[base+1] = excl + v0;
    if (base+2 < n) row[base+2] = excl + v0 + v1;
    if (base+3 < n) row[base+3] = excl + v0 + v1 + v2;
    __syncthreads();
  }
}

// ---------------- place: bin-ordered -> node-CSR (one block per bin) --------
// final rec: .x = other_id, .y = packed ea
__global__ __launch_bounds__(256) void place_kernel(
    const uint2* __restrict__ binned, const int* __restrict__ cursor,
    const int* __restrict__ row, uint2* __restrict__ rec, int N) {
  __shared__ int cur[BIN_W];
  int b = blockIdx.x;
  int n0 = b << BSHIFT;
  if (threadIdx.x < BIN_W) {
    int n = n0 + threadIdx.x;
    cur[threadIdx.x] = (n < N) ? row[n] : 0;
  }
  __syncthreads();
  int m = cursor[b]; if (m > CAP) m = CAP;
  const uint2* seg = binned + (size_t)b*CAP;
  for (int i = threadIdx.x; i < m; i += 256) {
    uint2 r = seg[i];
    int pos = atomicAdd(&cur[r.x >> 17], 1);
    rec[pos] = make_uint2(r.x & 0x1ffffu, r.y);
  }
}

// ---------------- per-iteration: node-level projections ---------------------
// Pi kept fp32 (read once per node); Pj packed bf16 (random-gathered E times).
__global__ __launch_bounds__(256) void node_pre_kernel(
    const float* __restrict__ H, const float* __restrict__ loop_col,
    const float* __restrict__ toW1, const float* __restrict__ frW1,
    const float* __restrict__ Wlp1c, const float* __restrict__ lpW1, const float* __restrict__ lpb1,
    float* __restrict__ Pti, unsigned short* __restrict__ Ptj,
    float* __restrict__ Pfi, unsigned short* __restrict__ Pfj,
    float* __restrict__ hlp, int N) {
  __shared__ float w[5*1056];   // 5 matrices, [k][f] stride 33
  __shared__ float hs[256];
  int t = threadIdx.x;
  #pragma unroll
  for (int r = 0; r < 4; r++) {
    int idx = r*256 + t;
    int fw = idx >> 5, k = idx & 31;
    w[0*1056 + k*33 + fw] = toW1[fw*66 + k];
    w[1*1056 + k*33 + fw] = toW1[fw*66 + 32 + k];
    w[2*1056 + k*33 + fw] = frW1[fw*66 + k];
    w[3*1056 + k*33 + fw] = frW1[fw*66 + 32 + k];
    w[4*1056 + k*33 + fw] = Wlp1c[fw*32 + k];
  }
  int node0 = blockIdx.x * 8;
  int gi = node0*32 + t;
  hs[t] = (gi < N*32) ? H[gi] : 0.f;
  __syncthreads();
  int nl = t >> 5, f = t & 31;
  int n = node0 + nl;
  if (n >= N) return;
  float a0=0.f, a1=0.f, a2=0.f, a3=0.f, a4=0.f;
  #pragma unroll
  for (int k = 0; k < 32; k++) {
    float hk = hs[nl*32 + k];
    a0 += w[0*1056 + k*33 + f]*hk;
    a1 += w[1*1056 + k*33 + f]*hk;
    a2 += w[2*1056 + k*33 + f]*hk;
    a3 += w[3*1056 + k*33 + f]*hk;
    a4 += w[4*1056 + k*33 + f]*hk;
  }
  int o = n*32 + f;
  Pti[o]=a0; Pfi[o]=a2;
  Ptj[o] = (unsigned short)pack_bf(a1);
  Pfj[o] = (unsigned short)pack_bf(a3);
  float hl = a4 + lpW1[f*65 + 64]*loop_col[n] + lpb1[f];
  hlp[o] = fmaxf(hl, 0.f);
}

// ---------------- per-iteration: edge aggregation (no atomics) --------------
__global__ __launch_bounds__(256) void agg_kernel(
    const float* __restrict__ Pi, const unsigned short* __restrict__ Pj,
    const int* __restrict__ row, const uint2* __restrict__ rec,
    const float* __restrict__ W1, const float* __restrict__ b1,
    float* __restrict__ acc_out, int N) {
  int t = blockIdx.x*blockDim.x + threadIdx.x;
  int n = t >> 5;
  if (n >= N) return;
  int f = t & 31;
  int start = row[n], end = row[n+1];
  float we0 = W1[f*66 + 64], we1 = W1[f*66 + 65];
  float base = Pi[n*32 + f] + b1[f];
  float s = 0.f;
  #pragma unroll 4
  for (int i = start; i < end; i++) {
    uint2 r = rec[i];
    int o = r.x;
    float e0 = __uint_as_float((r.y & 0xffffu) << 16);
    float e1 = __uint_as_float(r.y & 0xffff0000u);
    float pj = __uint_as_float(((unsigned int)Pj[o*32 + f]) << 16);
    float h = base + pj + we0*e0 + we1*e1;
    s += fmaxf(h, 0.f);
  }
  int c = end - start;
  acc_out[n*32 + f] = s / (float)(c > 0 ? c : 1);
}

// ---------------- per-iteration: GRU + H update + decode + loss -------------
// launch_bounds(128,1): lift VGPR cap so the 4x32-float input arrays live in
// registers (R3 had VGPR_Count=80 -> scratch spills -> 181us at 28% VALU).
// The only dynamically-indexed element (h[f] in the f-loop) goes through a
// conflict-free LDS slice (stride 33).
__global__ __launch_bounds__(128, 1) void node_update_kernel(
    float* __restrict__ H, const float* __restrict__ acc_to, const float* __restrict__ acc_fr,
    const float* __restrict__ hlp, const float* __restrict__ x, const float* __restrict__ y,
    const int* __restrict__ cnt_dst, const int* __restrict__ cnt_src,
    const float* __restrict__ Wih, const float* __restrict__ M_to, const float* __restrict__ M_fr,
    const float* __restrict__ M_lp, const float* __restrict__ v_to, const float* __restrict__ v_fr,
    const float* __restrict__ bihp, const float* __restrict__ bhh,
    const float* __restrict__ dW1, const float* __restrict__ db1,
    const float* __restrict__ dW2, const float* __restrict__ db2,
    float* __restrict__ Fout, float* __restrict__ loss_acc, int k_iter, int N) {
  __shared__ float hbuf[128*33];
  int t = threadIdx.x;
  int n = blockIdx.x*128 + t;
  float my_loss = 0.f;
  if (n < N) {
    float h[32], at[32], af[32], hl[32];
    const float4* p4;
    p4 = (const float4*)(H + n*32);
    #pragma unroll
    for (int q = 0; q < 8; q++) { float4 v = p4[q]; h[4*q]=v.x; h[4*q+1]=v.y; h[4*q+2]=v.z; h[4*q+3]=v.w; }
    p4 = (const float4*)(acc_to + n*32);
    #pragma unroll
    for (int q = 0; q < 8; q++) { float4 v = p4[q]; at[4*q]=v.x; at[4*q+1]=v.y; at[4*q+2]=v.z; at[4*q+3]=v.w; }
    p4 = (const float4*)(acc_fr + n*32);
    #pragma unroll
    for (int q = 0; q < 8; q++) { float4 v = p4[q]; af[4*q]=v.x; af[4*q+1]=v.y; af[4*q+2]=v.z; af[4*q+3]=v.w; }
    p4 = (const float4*)(hlp + n*32);
    #pragma unroll
    for (int q = 0; q < 8; q++) { float4 v = p4[q]; hl[4*q]=v.x; hl[4*q+1]=v.y; hl[4*q+2]=v.z; hl[4*q+3]=v.w; }
    // old h -> LDS slice (own slice only; no barrier needed)
    #pragma unroll
    for (int q = 0; q < 32; q++) hbuf[t*33 + q] = h[q];
    float gt = cnt_dst[n] > 0 ? 1.f : 0.f;
    float gf = cnt_src[n] > 0 ? 1.f : 0.f;
    float x0 = x[n*3], x1 = x[n*3+1], x2 = x[n*3+2];

    #pragma unroll 1
    for (int f = 0; f < 32; f++) {
      const float* wr = Wih + f*131;
      const float* wz = Wih + (f+32)*131;
      const float* wn = Wih + (f+64)*131;
      float ar = bihp[f]    + gt*v_to[f]    + gf*v_fr[f];
      float az = bihp[f+32] + gt*v_to[f+32] + gf*v_fr[f+32];
      float an = bihp[f+64] + gt*v_to[f+64] + gf*v_fr[f+64];
      #pragma unroll
      for (int k = 0; k < 32; k++) { float v = h[k];  ar += wr[k]*v; az += wz[k]*v; an += wn[k]*v; }
      const float* mr = M_to + f*32; const float* mz = M_to + (f+32)*32; const float* mn = M_to + (f+64)*32;
      #pragma unroll
      for (int k = 0; k < 32; k++) { float v = at[k]; ar += mr[k]*v; az += mz[k]*v; an += mn[k]*v; }
      mr = M_fr + f*32; mz = M_fr + (f+32)*32; mn = M_fr + (f+64)*32;
      #pragma unroll
      for (int k = 0; k < 32; k++) { float v = af[k]; ar += mr[k]*v; az += mz[k]*v; an += mn[k]*v; }
      mr = M_lp + f*32; mz = M_lp + (f+32)*32; mn = M_lp + (f+64)*32;
      #pragma unroll
      for (int k = 0; k < 32; k++) { float v = hl[k]; ar += mr[k]*v; az += mz[k]*v; an += mn[k]*v; }
      ar += wr[128]*x0 + wr[129]*x1 + wr[130]*x2;
      az += wz[128]*x0 + wz[129]*x1 + wz[130]*x2;
      an += wn[128]*x0 + wn[129]*x1 + wn[130]*x2;
      float rr = 1.f/(1.f + __expf(-(ar + bhh[f])));
      float zz = 1.f/(1.f + __expf(-(az + bhh[f+32])));
      float nv = tanhf(an + rr*bhh[f+64]);
      float hold = hbuf[t*33 + f];           // dynamic f: LDS, conflict-free
      hbuf[t*33 + f] = (1.f - zz)*nv*0.5f + hold;
    }

    // new h back to registers; write H once, vectorized
    float hn[32];
    #pragma unroll
    for (int q = 0; q < 32; q++) hn[q] = hbuf[t*33 + q];
    float4* o4 = (float4*)(H + n*32);
    #pragma unroll
    for (int q = 0; q < 8; q++) o4[q] = make_float4(hn[4*q], hn[4*q+1], hn[4*q+2], hn[4*q+3]);

    float F0 = db2[0], F1 = db2[1];
    #pragma unroll 1
    for (int f = 0; f < 32; f++) {
      float a = db1[f];
      const float* wd = dW1 + f*32;
      #pragma unroll
      for (int k = 0; k < 32; k++) a += wd[k]*hn[k];
      a = fmaxf(a, 0.f);
      F0 += dW2[f]*a;
      F1 += dW2[32+f]*a;
    }
    float2 fo; fo.x = F0; fo.y = F1;
    ((float2*)Fout)[n] = fo;
    float e0 = F0 - y[n*2], e1 = F1 - y[n*2+1];
    my_loss = e0*e0 + e1*e1;
  }
  #pragma unroll
  for (int off = 32; off > 0; off >>= 1) my_loss += __shfl_down(my_loss, off, 64);
  __shared__ float ls[2];
  int wid = t >> 6;
  if ((t & 63) == 0) ls[wid] = my_loss;
  __syncthreads();
  if (t == 0) atomicAdd(&loss_acc[k_iter], ls[0] + ls[1]);
}

__global__ void finalize_kernel(const float* __restrict__ loss_acc, float* __restrict__ out, int N) {
  if (threadIdx.x == 0 && blockIdx.x == 0) {
    float inv = 1.f/(2.f*(float)N);
    float l0 = loss_acc[0]*inv, l1 = loss_acc[1]*inv, l2 = loss_acc[2]*inv, l3 = loss_acc[3]*inv;
    out[0] = l0*0.729f + l1*0.81f + l2*0.9f + l3;   // gamma^{3,2,1,0}
    out[1] = l0; out[2] = l1; out[3] = l2; out[4] = l3;
  }
}

// ---------------------------------------------------------------------------
extern "C" void kernel_launch(void* const* d_in, const int* in_sizes, int n_in,
                              void* d_out, int out_size, void* d_ws, size_t ws_size,
                              hipStream_t stream) {
  const float* x    = (const float*)d_in[0];
  const float* y    = (const float*)d_in[1];
  const int*   ei   = (const int*)  d_in[2];
  const float* ea   = (const float*)d_in[3];
  const float* toW1 = (const float*)d_in[4];  const float* tob1 = (const float*)d_in[5];
  const float* toW2 = (const float*)d_in[6];  const float* tob2 = (const float*)d_in[7];
  const float* frW1 = (const float*)d_in[8];  const float* frb1 = (const float*)d_in[9];
  const float* frW2 = (const float*)d_in[10]; const float* frb2 = (const float*)d_in[11];
  const float* lpW1 = (const float*)d_in[12]; const float* lpb1 = (const float*)d_in[13];
  const float* lpW2 = (const float*)d_in[14]; const float* lpb2 = (const float*)d_in[15];
  const float* gWih = (const float*)d_in[16]; const float* gbih = (const float*)d_in[17];
  const float* gbhh = (const float*)d_in[19];           // gru_Whh dead: h0 = 0
  const float* dW1  = (const float*)d_in[20]; const float* db1  = (const float*)d_in[21];
  const float* dW2  = (const float*)d_in[22]; const float* db2  = (const float*)d_in[23];
  const int N = in_sizes[0] / 3;
  const int E = in_sizes[3] / 2;
  const int NB = (N + BIN_W - 1) >> BSHIFT;        // 782
  const int G  = (N + 1023) >> 10;                 // 98 scan blocks

  char* p = (char*)d_ws;
  auto carve = [&](size_t bytes) -> void* {
    void* r = (void*)p;
    p += (bytes + 255) & ~(size_t)255;
    return r;
  };
  // zeroed region first (single memset)
  float* H         = (float*)carve((size_t)N*32*4);
  float* loop_col  = (float*)carve((size_t)N*4);
  int*   cursor_to = (int*)  carve((size_t)NB*4);
  int*   cursor_fr = (int*)  carve((size_t)NB*4);
  float* loss_acc  = (float*)carve(64);
  size_t zero_bytes = (size_t)(p - (char*)d_ws);
  int*    row_to   = (int*)  carve((size_t)(N+1)*4);
  int*    row_fr   = (int*)  carve((size_t)(N+1)*4);
  int*    cnt_dst  = (int*)  carve((size_t)N*4);
  int*    cnt_src  = (int*)  carve((size_t)N*4);
  int*    part     = (int*)  carve((size_t)2*G*4);
  uint2*  binned_to= (uint2*)carve((size_t)NB*CAP*8);
  uint2*  binned_fr= (uint2*)carve((size_t)NB*CAP*8);
  uint2*  rec_to   = (uint2*)carve((size_t)E*8);
  uint2*  rec_fr   = (uint2*)carve((size_t)E*8);
  float*  Pti      = (float*)carve((size_t)N*32*4);
  float*  Pfi      = (float*)carve((size_t)N*32*4);
  unsigned short* Ptj = (unsigned short*)carve((size_t)N*32*2);
  unsigned short* Pfj = (unsigned short*)carve((size_t)N*32*2);
  float*  hlp      = (float*)carve((size_t)N*32*4);
  float*  acc_to   = (float*)carve((size_t)N*32*4);
  float*  acc_fr   = (float*)carve((size_t)N*32*4);
  float*  M_to     = (float*)carve(96*32*4);
  float*  M_fr     = (float*)carve(96*32*4);
  float*  M_lp     = (float*)carve(96*32*4);
  float*  v_to     = (float*)carve(96*4);
  float*  v_fr     = (float*)carve(96*4);
  float*  bihp     = (float*)carve(96*4);
  float*  Wlp1c    = (float*)carve(32*32*4);

  hipMemsetAsync(d_ws, 0, zero_bytes, stream);
  combine_kernel<<<17, 256, 0, stream>>>(gWih, gbih, toW2, tob2, frW2, frb2, lpW2, lpb2, lpW1,
                                         M_to, M_fr, M_lp, v_to, v_fr, bihp, Wlp1c);
  scatter_bin_kernel<<<(E+2047)/2048, 256, 0, stream>>>(ei, ea, cursor_to, cursor_fr,
                                                        binned_to, binned_fr, loop_col, E);
  bin_count_kernel<<<NB, 256, 0, stream>>>(binned_to, cursor_to, cnt_dst, N);
  bin_count_kernel<<<NB, 256, 0, stream>>>(binned_fr, cursor_fr, cnt_src, N);
  scan_part_kernel<<<G, 256, 0, stream>>>(cnt_dst, cnt_src, part, N, G);
  scan_mid_kernel<<<1, 256, 0, stream>>>(part, row_to, row_fr, N, G);
  scan_apply_kernel<<<G, 256, 0, stream>>>(cnt_dst, cnt_src, part, row_to, row_fr, N, G);
  place_kernel<<<NB, 256, 0, stream>>>(binned_to, cursor_to, row_to, rec_to, N);
  place_kernel<<<NB, 256, 0, stream>>>(binned_fr, cursor_fr, row_fr, rec_fr, N);

  float* Fout     = (float*)d_out;
  float* loss_out = (float*)d_out + (size_t)N*2;

  for (int k = 0; k < 4; k++) {
    node_pre_kernel<<<(N+7)/8, 256, 0, stream>>>(H, loop_col, toW1, frW1, Wlp1c, lpW1, lpb1,
                                                 Pti, Ptj, Pfi, Pfj, hlp, N);
    agg_kernel<<<(N*32+255)/256, 256, 0, stream>>>(Pti, Ptj, row_to, rec_to,
                                                   toW1, tob1, acc_to, N);
    agg_kernel<<<(N*32+255)/256, 256, 0, stream>>>(Pfi, Pfj, row_fr, rec_fr,
                                                   frW1, frb1, acc_fr, N);
    node_update_kernel<<<(N+127)/128, 128, 0, stream>>>(H, acc_to, acc_fr, hlp, x, y,
        cnt_dst, cnt_src, gWih, M_to, M_fr, M_lp, v_to, v_fr, bihp, gbhh,
        dW1, db1, dW2, db2, Fout, loss_acc, k, N);
  }
  finalize_kernel<<<1, 64, 0, stream>>>(loss_acc, loss_out, N);
}